// Round 1
// baseline (382.840 us; speedup 1.0000x reference)
//
#include <hip/hip_runtime.h>
#include <math.h>

#define WAVE 64

// Native clang vector type — required for __builtin_nontemporal_load.
typedef float nfloat4 __attribute__((ext_vector_type(4)));

// Shapes fixed by reference: B=64, T=2048, Q=512, K=512.

// ---------------------------------------------------------------------------
// Reduce-scatter + broadcast: input s[0..7] = per-lane partials of 8 rows.
// Output: every lane holds the FULL 64-lane sum of row r = (lane>>3)&7.
// 10 shuffles total vs 48 for the naive 6-step-butterfly-per-row.
// Stage xor32: low lanes keep rows 0..3, high lanes keep rows 4..7.
// Stage xor16: split again by bit4 (rows +2), xor8 by bit3 (rows +1),
// then a plain 3-step butterfly over bits 0..2 completes the sum.
// ---------------------------------------------------------------------------
__device__ __forceinline__ float reduce8(const float s[8]) {
    const int lane = (int)(threadIdx.x & 63);
    const bool hi32 = (lane & 32) != 0;
    float v[4];
    #pragma unroll
    for (int r = 0; r < 4; ++r) {
        float keep = hi32 ? s[r + 4] : s[r];
        float send = hi32 ? s[r] : s[r + 4];
        v[r] = keep + __shfl_xor(send, 32, WAVE);
    }
    const bool hi16 = (lane & 16) != 0;
    float w[2];
    #pragma unroll
    for (int r = 0; r < 2; ++r) {
        float keep = hi16 ? v[r + 2] : v[r];
        float send = hi16 ? v[r] : v[r + 2];
        w[r] = keep + __shfl_xor(send, 16, WAVE);
    }
    const bool hi8 = (lane & 8) != 0;
    float keep = hi8 ? w[1] : w[0];
    float send = hi8 ? w[0] : w[1];
    float x = keep + __shfl_xor(send, 8, WAVE);
    x += __shfl_xor(x, 4, WAVE);
    x += __shfl_xor(x, 2, WAVE);
    x += __shfl_xor(x, 1, WAVE);
    return x;
}

// ---------------------------------------------------------------------------
// Kernel 1: mids[b,k] = sum_q W[k,q] * query[b,q]
// One wave per 8 consecutive k for one b. W (1 MB) is L2/L3-resident.
// Also zeroes the 64 softmax denominators (workspace is poisoned per iter;
// this kernel precedes scores_kernel in stream order).
// ---------------------------------------------------------------------------
__global__ void mids_kernel(const float* __restrict__ W,
                            const float* __restrict__ query,
                            float* __restrict__ mids,
                            float* __restrict__ sums) {
    if (blockIdx.x == 0 && threadIdx.x < 64) sums[threadIdx.x] = 0.f;

    const int gwave = (int)((blockIdx.x * blockDim.x + threadIdx.x) >> 6);
    const int lane  = threadIdx.x & 63;
    const int b  = gwave >> 6;          // 64 waves per batch row (512/8)
    const int k0 = (gwave & 63) * 8;

    const float4* qrow = (const float4*)(query + (size_t)b * 512);
    const float4 q0 = qrow[lane];
    const float4 q1 = qrow[lane + 64];

    float s[8];
    #pragma unroll
    for (int r = 0; r < 8; ++r) {
        const float4* wrow = (const float4*)(W + (size_t)(k0 + r) * 512);
        float4 a = wrow[lane];
        float4 c = wrow[lane + 64];
        s[r] = a.x*q0.x + a.y*q0.y + a.z*q0.z + a.w*q0.w
             + c.x*q1.x + c.y*q1.y + c.z*q1.z + c.w*q1.w;
    }
    float x = reduce8(s);
    // Lanes 0,8,...,56 hold rows 0..7 -> 8 consecutive dwords, coalesced.
    if ((lane & 7) == 0)
        mids[(size_t)gwave * 8 + ((lane >> 3) & 7)] = x;
}

// ---------------------------------------------------------------------------
// Kernel 2: out[b,t] = expf(tanhf(key[b,t,:].mids[b,:] + bias))  (unnormalized)
// tanh in (-1,1) => exp cannot overflow => max-subtraction is unnecessary,
// so the softmax numerator fuses here and only a normalize pass remains.
// 16 rows per wave, two 8-row groups; 16 nontemporal float4 loads in flight
// per group. tanh/exp computed on ALL 64 lanes in parallel (was 16 serial
// divergent tanhf on lane 0). Per-wave exp-sum -> one atomicAdd into sums[b].
// ---------------------------------------------------------------------------
__global__ void scores_kernel(const float* __restrict__ key,
                              const float* __restrict__ mids,
                              const float* __restrict__ bias,
                              float* __restrict__ out,
                              float* __restrict__ sums) {
    const int gwave = (int)((blockIdx.x * blockDim.x + threadIdx.x) >> 6);
    const int lane  = threadIdx.x & 63;
    const int row0  = gwave * 16;          // flattened (b*T + t)
    const int b     = row0 >> 11;          // T = 2048

    const float4* mrow = (const float4*)(mids + (size_t)b * 512);
    const float4 m0 = mrow[lane];
    const float4 m1 = mrow[lane + 64];
    const float bv = bias[0];

    const nfloat4* kbase = (const nfloat4*)key + (size_t)row0 * 128;  // 128 f4/row

    float wave_sum = 0.f;

    #pragma unroll
    for (int g = 0; g < 2; ++g) {          // two 8-row groups
        const int r0 = g * 8;
        nfloat4 a[8], c[8];
        #pragma unroll
        for (int r = 0; r < 8; ++r) {
            a[r] = __builtin_nontemporal_load(&kbase[(size_t)(r0 + r) * 128 + lane]);
            c[r] = __builtin_nontemporal_load(&kbase[(size_t)(r0 + r) * 128 + lane + 64]);
        }
        float s[8];
        #pragma unroll
        for (int r = 0; r < 8; ++r) {
            s[r] = a[r].x*m0.x + a[r].y*m0.y + a[r].z*m0.z + a[r].w*m0.w
                 + c[r].x*m1.x + c[r].y*m1.y + c[r].z*m1.z + c[r].w*m1.w;
        }
        // Full sum of row (lane>>3)&7, on every lane.
        float x = reduce8(s);
        // Wave-parallel transcendental (each value computed 8x, but one issue).
        float e = expf(tanhf(x + bv));
        // Lanes 0,8,...,56 store rows 0..7 -> 8 consecutive dwords, coalesced.
        if ((lane & 7) == 0)
            out[(size_t)row0 + r0 + ((lane >> 3) & 7)] = e;
        // Sum of the 8 distinct row-values: butterfly over lane bits 3..5 only
        // (each row is replicated across bits 0..2, so this counts each once).
        float y = e;
        y += __shfl_xor(y, 8, WAVE);
        y += __shfl_xor(y, 16, WAVE);
        y += __shfl_xor(y, 32, WAVE);
        wave_sum += y;
    }
    if (lane == 0)
        atomicAdd(&sums[b], wave_sum);     // 64 addresses, 128 adds each
}

// ---------------------------------------------------------------------------
// Kernel 3: out[b,t] /= sums[b]. One float4 per thread, 32768 threads.
// b is uniform per block (512 f4 per row, 256 threads/block).
// ---------------------------------------------------------------------------
__global__ void normalize_kernel(float* __restrict__ out,
                                 const float* __restrict__ sums) {
    const int idx = (int)(blockIdx.x * blockDim.x + threadIdx.x);  // f4 index
    const int b   = idx >> 9;                                      // 512 f4 / row
    const float inv = 1.f / sums[b];
    float4* p = (float4*)out + idx;
    float4 v = *p;
    v.x *= inv; v.y *= inv; v.z *= inv; v.w *= inv;
    *p = v;
}

// ---------------------------------------------------------------------------
extern "C" void kernel_launch(void* const* d_in, const int* in_sizes, int n_in,
                              void* d_out, int out_size, void* d_ws, size_t ws_size,
                              hipStream_t stream) {
    const float* query = (const float*)d_in[0];   // [B, Q]
    const float* key   = (const float*)d_in[1];   // [B, T, K]
    const float* W     = (const float*)d_in[2];   // [K, Q]
    const float* bias  = (const float*)d_in[3];   // [1]
    float* out  = (float*)d_out;                  // [B, T]
    float* mids = (float*)d_ws;                   // [B, K] scratch (128 KB)
    float* sums = mids + 64 * 512;                // [B] softmax denominators

    // 1) mids: 4096 waves (8 k-outputs each) -> 1024 blocks; also zeroes sums
    mids_kernel<<<1024, 256, 0, stream>>>(W, query, mids, sums);

    // 2) scores+exp+denominator: 8192 waves (16 rows each) -> 2048 blocks
    scores_kernel<<<2048, 256, 0, stream>>>(key, mids, bias, out, sums);

    // 3) normalize: 64*2048/4 = 32768 float4 -> 128 blocks of 256
    normalize_kernel<<<128, 256, 0, stream>>>(out, sums);
}